// Round 6
// baseline (176.010 us; speedup 1.0000x reference)
//
#include <hip/hip_runtime.h>

typedef _Float16 half2v __attribute__((ext_vector_type(2)));

// ---- zero small stats buffer (ws is poisoned 0xAA each call) ----
__global__ void k_zero(float* __restrict__ p, int n){
  int i = blockIdx.x * blockDim.x + threadIdx.x;
  if (i < n) p[i] = 0.f;
}

// ---- convert w_span fp32 -> fp16 once (feeds k_main's v_dot2 path) ----
__global__ void k_prep(const float* __restrict__ wspan, _Float16* __restrict__ w16){
  int i = blockIdx.x * 256 + threadIdx.x;
  if (i < 12544) w16[i] = (_Float16)wspan[i];
}

// ---- fused front-end: dw3x3 + pw1x1 + reduce1x1 + BN stats, one input pass ----
// block = 16x8 px tile; 256 threads = 2 halves x 128 px.
// half 0: pw outputs 0..31,  red ch 0..7;  half 1: pw 32..63, red ch 8..15.
__launch_bounds__(256, 2)
__global__ void k_front(const float* __restrict__ in, const float* __restrict__ wdw,
                        const float* __restrict__ wpw, const float* __restrict__ wred,
                        float* __restrict__ h, float* __restrict__ r,
                        float* __restrict__ stats){
  __shared__ float s_in[16][10][19];                 // 16 ch chunk, 10x18 halo (+1 pad)
  __shared__ float sw[4][16];
  int t = threadIdx.x;
  int half = t >> 7;
  int px = t & 127;
  int lx = px & 15, ly = px >> 4;                    // ly 0..7
  int blk = blockIdx.x;
  int tile = blk & 127, b = blk >> 7;
  int x0 = (tile & 7) << 4, y0 = (tile >> 3) << 3;
  const float* inb = in + ((long)b << 20);

  float pacc[32], racc[8];
  #pragma unroll
  for (int j = 0; j < 32; j++) pacc[j] = 0.f;
  #pragma unroll
  for (int j = 0; j < 8; j++) racc[j] = 0.f;

  for (int q = 0; q < 4; q++){
    int c0 = q << 4;
    __syncthreads();                                 // previous chunk fully consumed
    for (int i = t; i < 2880; i += 256){             // 16 ch x 10 x 18 halo stage
      int c = i / 180, rem = i - c * 180;
      int ry = rem / 18, rx = rem - ry * 18;
      int yy = y0 + ry - 1, xx = x0 + rx - 1;
      float v = 0.f;
      if ((unsigned)yy < 128u && (unsigned)xx < 128u)
        v = inb[((long)(c0 + c) << 14) + (yy << 7) + xx];
      s_in[c][ry][rx] = v;
    }
    __syncthreads();

    float dwv[16], cv[16];
    #pragma unroll
    for (int c = 0; c < 16; c++){
      const float* wd = wdw + (c0 + c) * 9;          // uniform -> s_load
      float s = 0.f, center = 0.f;
      #pragma unroll
      for (int dy = 0; dy < 3; dy++)
        #pragma unroll
        for (int dx = 0; dx < 3; dx++){
          float v = s_in[c][ly + dy][lx + dx];
          if (dy == 1 && dx == 1) center = v;
          s += v * wd[dy * 3 + dx];
        }
      dwv[c] = s; cv[c] = center;
    }
    // pw partial: 32 outputs for this half
    #pragma unroll
    for (int j = 0; j < 32; j++){
      const float* wr = wpw + ((half << 5) + j) * 64 + c0;  // uniform -> s_load x16
      float s = pacc[j];
      #pragma unroll
      for (int c = 0; c < 16; c++) s += dwv[c] * wr[c];
      pacc[j] = s;
    }
    // red partial (raw input!): 8 channels for this half
    #pragma unroll
    for (int j = 0; j < 8; j++){
      const float* wr = wred + ((half << 3) + j) * 64 + c0;
      float s = racc[j];
      #pragma unroll
      for (int c = 0; c < 16; c++) s += cv[c] * wr[c];
      racc[j] = s;
    }
  }

  long sp = ((long)(y0 + ly) << 7) + x0 + lx;
  float* hb = h + ((long)b << 20) + sp;
  #pragma unroll
  for (int j = 0; j < 32; j++) hb[(long)((half << 5) + j) << 14] = pacc[j];
  float* rb = r + ((long)b << 18) + sp;
  #pragma unroll
  for (int j = 0; j < 8; j++) rb[(long)((half << 3) + j) << 14] = racc[j];

  // BN stats: wave shuffle-reduce; waves 0,1 = ch 0-7, waves 2,3 = ch 8-15
  int lane = t & 63, wv = t >> 6;
  #pragma unroll
  for (int j = 0; j < 8; j++){
    float v = racc[j], s2 = racc[j] * racc[j];
    #pragma unroll
    for (int off = 32; off > 0; off >>= 1){
      v  += __shfl_down(v,  off, 64);
      s2 += __shfl_down(s2, off, 64);
    }
    if (lane == 0){ sw[wv][2 * j] = v; sw[wv][2 * j + 1] = s2; }
  }
  __syncthreads();
  if (t < 16)       atomicAdd(&stats[t],  sw[0][t] + sw[1][t]);
  else if (t < 32)  atomicAdd(&stats[t],  sw[2][t - 16] + sw[3][t - 16]);
}

// ---- BN finalize: scale/bias per channel (training-mode, biased var) ----
__global__ void k_bn(const float* __restrict__ stats, const float* __restrict__ gamma,
                     const float* __restrict__ beta, float* __restrict__ sb){
  int c = threadIdx.x;
  if (c < 16){
    const float n = 65536.f;                         // B*H*W
    float mean = stats[2 * c] / n;
    float var  = stats[2 * c + 1] / n - mean * mean;
    float inv  = rsqrtf(var + 1e-5f);
    float sc   = gamma[c] * inv;
    sb[2 * c]     = sc;
    sb[2 * c + 1] = beta[c] - mean * sc;
  }
}

// ---- main involution: per (b, g, 16x16 tile); kern-gen via v_dot2_f32_f16 ----
__launch_bounds__(256)
__global__ void k_main(const float* __restrict__ h, const float* __restrict__ r,
                       const float* __restrict__ sb, const _Float16* __restrict__ w16,
                       float* __restrict__ out){
  __shared__ float4 s_h4[22][24];                    // [row][col] -> 4 cg contiguous
  int t = threadIdx.x;
  int g = blockIdx.y, b = blockIdx.z;
  int tx0 = (blockIdx.x & 7) << 4, ty0 = (blockIdx.x >> 3) << 4;

  const float* hp = h + (((long)(b * 64 + g * 4)) << 14);
  for (int p = t; p < 484; p += 256){                // 22x22 halo points
    int ry = p / 22, rx = p - ry * 22;
    int yy = ty0 + ry - 3, xx = tx0 + rx - 3;
    float4 v = make_float4(0.f, 0.f, 0.f, 0.f);
    if ((unsigned)yy < 128u && (unsigned)xx < 128u){
      int o = (yy << 7) + xx;
      v.x = hp[o];
      v.y = hp[o + 16384];
      v.z = hp[o + 32768];
      v.w = hp[o + 49152];
    }
    s_h4[ry][rx] = v;
  }

  int ltx = t & 15, lty = t >> 4;
  int px = tx0 + ltx, py = ty0 + lty;
  const float* rp = r + ((long)b << 18) + (py << 7) + px;
  float rv[16];
  #pragma unroll
  for (int c = 0; c < 16; c++){
    float v = rp[(long)c << 14];
    rv[c] = fmaxf(v * sb[2 * c] + sb[2 * c + 1], 0.f);
  }
#if __has_builtin(__builtin_amdgcn_fdot2)
  half2v rv2[8];
  #pragma unroll
  for (int j = 0; j < 8; j++){
    half2v pk; pk[0] = (_Float16)rv[2 * j]; pk[1] = (_Float16)rv[2 * j + 1];
    rv2[j] = pk;
  }
#endif
  __syncthreads();

  const _Float16* wg = w16 + g * 784;                // uniform -> scalar pipe
#if __has_builtin(__builtin_amdgcn_fdot2)
  const half2v* wg2 = (const half2v*)wg;
#endif
  float acc0 = 0.f, acc1 = 0.f, acc2 = 0.f, acc3 = 0.f;
  #pragma unroll
  for (int kh = 0; kh < 7; kh++){
    #pragma unroll
    for (int kw = 0; kw < 7; kw++){
      int k = kh * 7 + kw;
      float kv = 0.f;
#if __has_builtin(__builtin_amdgcn_fdot2)
      #pragma unroll
      for (int j = 0; j < 8; j++)
        kv = __builtin_amdgcn_fdot2(rv2[j], wg2[k * 8 + j], kv, false);
#else
      #pragma unroll
      for (int c = 0; c < 16; c++) kv += rv[c] * (float)wg[k * 16 + c];
#endif
      float4 hv = s_h4[lty + kh][ltx + kw];
      acc0 += kv * hv.x;
      acc1 += kv * hv.y;
      acc2 += kv * hv.z;
      acc3 += kv * hv.w;
    }
  }

  long obase = (((long)(b * 64 + g * 4)) << 14) + (py << 7) + px;
  out[obase]         = acc0;
  out[obase + 16384] = acc1;
  out[obase + 32768] = acc2;
  out[obase + 49152] = acc3;
}

extern "C" void kernel_launch(void* const* d_in, const int* in_sizes, int n_in,
                              void* d_out, int out_size, void* d_ws, size_t ws_size,
                              hipStream_t stream){
  const float* in       = (const float*)d_in[0];
  const float* w_dw     = (const float*)d_in[1];
  const float* w_pw     = (const float*)d_in[2];
  const float* gamma    = (const float*)d_in[3];
  const float* beta     = (const float*)d_in[4];
  const float* w_reduce = (const float*)d_in[5];
  const float* w_span   = (const float*)d_in[6];
  float* out = (float*)d_out;

  float* ws    = (float*)d_ws;
  float* h     = ws;                    // 4194304 floats
  float* r     = ws + 4194304;          // 1048576 floats
  float* stats = ws + 5242880;          // 32 floats
  float* sb    = ws + 5242912;          // 32 floats
  _Float16* w16 = (_Float16*)(ws + 5242944);  // 12544 halfs

  k_zero <<<1, 64, 0, stream>>>(stats, 32);
  k_prep <<<49, 256, 0, stream>>>(w_span, w16);
  k_front<<<512, 256, 0, stream>>>(in, w_dw, w_pw, w_reduce, h, r, stats);
  k_bn   <<<1, 16, 0, stream>>>(stats, gamma, beta, sb);
  dim3 grid(64, 16, 4);
  k_main <<<grid, 256, 0, stream>>>(h, r, sb, w16, out);
}

// Round 7
// 163.309 us; speedup vs baseline: 1.0778x; 1.0778x over previous
//
#include <hip/hip_runtime.h>

typedef _Float16 half2v __attribute__((ext_vector_type(2)));

// ---- zero small stats buffer (ws is poisoned 0xAA each call) ----
__global__ void k_zero(float* __restrict__ p, int n){
  int i = blockIdx.x * blockDim.x + threadIdx.x;
  if (i < n) p[i] = 0.f;
}

// ---- convert w_span fp32 -> fp16 once (feeds k_main's v_dot2 path) ----
__global__ void k_prep(const float* __restrict__ wspan, _Float16* __restrict__ w16){
  int i = blockIdx.x * 256 + threadIdx.x;
  if (i < 12544) w16[i] = (_Float16)wspan[i];
}

// ---- fused front-end v2: dw3x3 + pw1x1 + reduce1x1 + BN stats ----
// 8x8 px tile, 1024 blocks (4/CU). wave = full tile (lane=px).
// Per 16-ch chunk: all stage -> wave w dw-convs its 4 channels -> LDS ->
// wave w accumulates pw outputs 16w..16w+15 and red ch 4w..4w+3.
__launch_bounds__(256, 4)
__global__ void k_front(const float* __restrict__ in, const float* __restrict__ wdw,
                        const float* __restrict__ wpw, const float* __restrict__ wred,
                        float* __restrict__ h, float* __restrict__ r,
                        float* __restrict__ stats){
  __shared__ float4 s_in4[4][10][12];                // [c4][ry][rx] 4ch contiguous
  __shared__ float4 s_dw4[4][64];                    // [c4][px]
  __shared__ float4 s_cv4[4][64];                    // [c4][px] raw center vals
  __shared__ float  s_red[4][8];
  int t = threadIdx.x;
  int w = t >> 6, lane = t & 63;
  int lx = lane & 7, ly = lane >> 3;
  int blk = blockIdx.x;
  int tile = blk & 255, b = blk >> 8;
  int x0 = (tile & 15) << 3, y0 = (tile >> 4) << 3;
  const float* inb = in + ((long)b << 20);

  float pacc[16], racc[4];
  #pragma unroll
  for (int j = 0; j < 16; j++) pacc[j] = 0.f;
  #pragma unroll
  for (int j = 0; j < 4; j++) racc[j] = 0.f;

  for (int q = 0; q < 4; q++){
    int c0 = q << 4;
    __syncthreads();                                 // s_in4 free (prev dw done)
    for (int i = t; i < 400; i += 256){              // 4 c4-groups x 10x10 halo
      int c4 = i / 100, pos = i - c4 * 100;
      int ry = pos / 10, rx = pos - ry * 10;
      int yy = y0 + ry - 1, xx = x0 + rx - 1;
      float4 v = make_float4(0.f, 0.f, 0.f, 0.f);
      if ((unsigned)yy < 128u && (unsigned)xx < 128u){
        long base = ((long)(c0 + (c4 << 2)) << 14) + (yy << 7) + xx;
        v.x = inb[base];
        v.y = inb[base + 16384];
        v.z = inb[base + 32768];
        v.w = inb[base + 49152];
      }
      s_in4[c4][ry][rx] = v;
    }
    __syncthreads();

    // dw: wave w convolves its 4 channels (c0+4w .. +3), once per px
    {
      const float* wd = wdw + (c0 + (w << 2)) * 9;   // uniform -> s_load
      float4 a = make_float4(0.f, 0.f, 0.f, 0.f);
      float4 cv = make_float4(0.f, 0.f, 0.f, 0.f);
      #pragma unroll
      for (int dy = 0; dy < 3; dy++){
        #pragma unroll
        for (int dx = 0; dx < 3; dx++){
          float4 v = s_in4[w][ly + dy][lx + dx];
          int k = dy * 3 + dx;
          a.x += v.x * wd[k];
          a.y += v.y * wd[9 + k];
          a.z += v.z * wd[18 + k];
          a.w += v.w * wd[27 + k];
          if (k == 4) cv = v;
        }
      }
      s_dw4[w][lane] = a;
      s_cv4[w][lane] = cv;
    }
    __syncthreads();

    float4 d0 = s_dw4[0][lane], d1 = s_dw4[1][lane];
    float4 d2 = s_dw4[2][lane], d3 = s_dw4[3][lane];
    float4 e0 = s_cv4[0][lane], e1 = s_cv4[1][lane];
    float4 e2 = s_cv4[2][lane], e3 = s_cv4[3][lane];
    #pragma unroll
    for (int j = 0; j < 16; j++){
      const float* wr = wpw + ((w << 4) + j) * 64 + c0;  // uniform -> s_load
      float s = pacc[j];
      s += d0.x * wr[0]  + d0.y * wr[1]  + d0.z * wr[2]  + d0.w * wr[3];
      s += d1.x * wr[4]  + d1.y * wr[5]  + d1.z * wr[6]  + d1.w * wr[7];
      s += d2.x * wr[8]  + d2.y * wr[9]  + d2.z * wr[10] + d2.w * wr[11];
      s += d3.x * wr[12] + d3.y * wr[13] + d3.z * wr[14] + d3.w * wr[15];
      pacc[j] = s;
    }
    #pragma unroll
    for (int j = 0; j < 4; j++){
      const float* wr = wred + ((w << 2) + j) * 64 + c0;
      float s = racc[j];
      s += e0.x * wr[0]  + e0.y * wr[1]  + e0.z * wr[2]  + e0.w * wr[3];
      s += e1.x * wr[4]  + e1.y * wr[5]  + e1.z * wr[6]  + e1.w * wr[7];
      s += e2.x * wr[8]  + e2.y * wr[9]  + e2.z * wr[10] + e2.w * wr[11];
      s += e3.x * wr[12] + e3.y * wr[13] + e3.z * wr[14] + e3.w * wr[15];
      racc[j] = s;
    }
  }

  long sp = ((long)(y0 + ly) << 7) + x0 + lx;
  float* hb = h + ((long)b << 20) + sp;
  #pragma unroll
  for (int j = 0; j < 16; j++) hb[(long)((w << 4) + j) << 14] = pacc[j];
  float* rb = r + ((long)b << 18) + sp;
  #pragma unroll
  for (int j = 0; j < 4; j++) rb[(long)((w << 2) + j) << 14] = racc[j];

  // BN stats: wave w owns channels 4w..4w+3
  #pragma unroll
  for (int j = 0; j < 4; j++){
    float v = racc[j], s2 = racc[j] * racc[j];
    #pragma unroll
    for (int off = 32; off > 0; off >>= 1){
      v  += __shfl_down(v,  off, 64);
      s2 += __shfl_down(s2, off, 64);
    }
    if (lane == 0){ s_red[w][2 * j] = v; s_red[w][2 * j + 1] = s2; }
  }
  __syncthreads();
  if (t < 32) atomicAdd(&stats[t], s_red[t >> 3][t & 7]);
}

// ---- BN finalize: scale/bias per channel (training-mode, biased var) ----
__global__ void k_bn(const float* __restrict__ stats, const float* __restrict__ gamma,
                     const float* __restrict__ beta, float* __restrict__ sb){
  int c = threadIdx.x;
  if (c < 16){
    const float n = 65536.f;                         // B*H*W
    float mean = stats[2 * c] / n;
    float var  = stats[2 * c + 1] / n - mean * mean;
    float inv  = rsqrtf(var + 1e-5f);
    float sc   = gamma[c] * inv;
    sb[2 * c]     = sc;
    sb[2 * c + 1] = beta[c] - mean * sc;
  }
}

// ---- main involution: per (b, g, 16x16 tile); kern-gen via v_dot2_f32_f16 ----
__launch_bounds__(256)
__global__ void k_main(const float* __restrict__ h, const float* __restrict__ r,
                       const float* __restrict__ sb, const _Float16* __restrict__ w16,
                       float* __restrict__ out){
  __shared__ float4 s_h4[22][24];                    // [row][col] -> 4 cg contiguous
  int t = threadIdx.x;
  int g = blockIdx.y, b = blockIdx.z;
  int tx0 = (blockIdx.x & 7) << 4, ty0 = (blockIdx.x >> 3) << 4;

  const float* hp = h + (((long)(b * 64 + g * 4)) << 14);
  for (int p = t; p < 484; p += 256){                // 22x22 halo points
    int ry = p / 22, rx = p - ry * 22;
    int yy = ty0 + ry - 3, xx = tx0 + rx - 3;
    float4 v = make_float4(0.f, 0.f, 0.f, 0.f);
    if ((unsigned)yy < 128u && (unsigned)xx < 128u){
      int o = (yy << 7) + xx;
      v.x = hp[o];
      v.y = hp[o + 16384];
      v.z = hp[o + 32768];
      v.w = hp[o + 49152];
    }
    s_h4[ry][rx] = v;
  }

  int ltx = t & 15, lty = t >> 4;
  int px = tx0 + ltx, py = ty0 + lty;
  const float* rp = r + ((long)b << 18) + (py << 7) + px;
  float rv[16];
  #pragma unroll
  for (int c = 0; c < 16; c++){
    float v = rp[(long)c << 14];
    rv[c] = fmaxf(v * sb[2 * c] + sb[2 * c + 1], 0.f);
  }
#if __has_builtin(__builtin_amdgcn_fdot2)
  half2v rv2[8];
  #pragma unroll
  for (int j = 0; j < 8; j++){
    half2v pk; pk[0] = (_Float16)rv[2 * j]; pk[1] = (_Float16)rv[2 * j + 1];
    rv2[j] = pk;
  }
#endif
  __syncthreads();

  const _Float16* wg = w16 + g * 784;                // uniform -> scalar pipe
#if __has_builtin(__builtin_amdgcn_fdot2)
  const half2v* wg2 = (const half2v*)wg;
#endif
  float acc0 = 0.f, acc1 = 0.f, acc2 = 0.f, acc3 = 0.f;
  #pragma unroll
  for (int kh = 0; kh < 7; kh++){
    #pragma unroll
    for (int kw = 0; kw < 7; kw++){
      int k = kh * 7 + kw;
      float kv = 0.f;
#if __has_builtin(__builtin_amdgcn_fdot2)
      #pragma unroll
      for (int j = 0; j < 8; j++)
        kv = __builtin_amdgcn_fdot2(rv2[j], wg2[k * 8 + j], kv, false);
#else
      #pragma unroll
      for (int c = 0; c < 16; c++) kv += rv[c] * (float)wg[k * 16 + c];
#endif
      float4 hv = s_h4[lty + kh][ltx + kw];
      acc0 += kv * hv.x;
      acc1 += kv * hv.y;
      acc2 += kv * hv.z;
      acc3 += kv * hv.w;
    }
  }

  long obase = (((long)(b * 64 + g * 4)) << 14) + (py << 7) + px;
  out[obase]         = acc0;
  out[obase + 16384] = acc1;
  out[obase + 32768] = acc2;
  out[obase + 49152] = acc3;
}

extern "C" void kernel_launch(void* const* d_in, const int* in_sizes, int n_in,
                              void* d_out, int out_size, void* d_ws, size_t ws_size,
                              hipStream_t stream){
  const float* in       = (const float*)d_in[0];
  const float* w_dw     = (const float*)d_in[1];
  const float* w_pw     = (const float*)d_in[2];
  const float* gamma    = (const float*)d_in[3];
  const float* beta     = (const float*)d_in[4];
  const float* w_reduce = (const float*)d_in[5];
  const float* w_span   = (const float*)d_in[6];
  float* out = (float*)d_out;

  float* ws    = (float*)d_ws;
  float* h     = ws;                    // 4194304 floats
  float* r     = ws + 4194304;          // 1048576 floats
  float* stats = ws + 5242880;          // 32 floats
  float* sb    = ws + 5242912;          // 32 floats
  _Float16* w16 = (_Float16*)(ws + 5242944);  // 12544 halfs

  k_zero <<<1, 64, 0, stream>>>(stats, 32);
  k_prep <<<49, 256, 0, stream>>>(w_span, w16);
  k_front<<<1024, 256, 0, stream>>>(in, w_dw, w_pw, w_reduce, h, r, stats);
  k_bn   <<<1, 16, 0, stream>>>(stats, gamma, beta, sb);
  dim3 grid(64, 16, 4);
  k_main <<<grid, 256, 0, stream>>>(h, r, sb, w16, out);
}